// Round 7
// baseline (277.277 us; speedup 1.0000x reference)
//
#include <hip/hip_runtime.h>
#include <cstdint>
#include <cstddef>

#define DIMC 768
#define NHH  12
#define NSEQ 1024
#define HD   64

#define SX  6291456   // x elems (8*1024*768)
#define SW1 1769472   // qkv_w elems
#define SW2 589824    // proj_w elems

#define RELN 3969     // 63*63 table entries per head
#define RELP 4032     // padded stride (lane-63 overread stays in-bounds)

typedef _Float16 f16x8 __attribute__((ext_vector_type(8)));
typedef _Float16 f16x4 __attribute__((ext_vector_type(4)));
typedef float    f32x4 __attribute__((ext_vector_type(4)));
typedef float    f32x16 __attribute__((ext_vector_type(16)));

__device__ inline void gld16(const _Float16* g, _Float16* l) {
  __builtin_amdgcn_global_load_lds(
      (const __attribute__((address_space(1))) void*)g,
      (__attribute__((address_space(3))) void*)l, 16, 0, 0);
}

// ---------------------------------------------------------------------------
// Fused fp32 -> fp16 cast of x | qkv_w | proj_w into one contiguous ws region.
// ---------------------------------------------------------------------------
__global__ __launch_bounds__(256) void cast_f16(
    const float* __restrict__ x, const float* __restrict__ w1,
    const float* __restrict__ w2, _Float16* __restrict__ dst) {
  const long long t = (long long)blockIdx.x * 256 + threadIdx.x;
  const long long i = t * 8;
  const float* src; long long off;
  if (i < SX) { src = x; off = i; }
  else if (i < SX + SW1) { src = w1; off = i - SX; }
  else { src = w2; off = i - (SX + SW1); }
  const float4 a = *(const float4*)(src + off);
  const float4 b = *(const float4*)(src + off + 4);
  f16x8 o;
  o[0] = (_Float16)a.x; o[1] = (_Float16)a.y; o[2] = (_Float16)a.z; o[3] = (_Float16)a.w;
  o[4] = (_Float16)b.x; o[5] = (_Float16)b.y; o[6] = (_Float16)b.z; o[7] = (_Float16)b.w;
  *(f16x8*)(dst + i) = o;
}

// ---------------------------------------------------------------------------
// MFMA GEMM: C[m,o] = sum_k A[m,k]*W[o,k].  128x128 tile, BK=32, m97 structure.
// EPI==0: scatter f16 Q(+bias,*0.125)/K/V(+bias) into [B,NH,N,hd]
// EPI==1: fp32 outF[m*768+o] = acc + b0[o]
// ---------------------------------------------------------------------------
template <int EPI>
__global__ __launch_bounds__(256) void gemm_mfma(
    const _Float16* __restrict__ A, const _Float16* __restrict__ W,
    const float* __restrict__ b0, const float* __restrict__ b1,
    float* __restrict__ outF, _Float16* __restrict__ oq,
    _Float16* __restrict__ ok, _Float16* __restrict__ ov) {
  __shared__ _Float16 Alds[128 * 32];
  __shared__ _Float16 Blds[128 * 32];

  const int tid = threadIdx.x;
  const int w = tid >> 6, lane = tid & 63, quad = lane >> 4, l16 = lane & 15;
  const int m0 = blockIdx.y * 128, o0 = blockIdx.x * 128;
  const int wr = (w >> 1) * 64, wc = (w & 1) * 64;

  f32x4 acc[4][4];
#pragma unroll
  for (int i = 0; i < 4; i++)
#pragma unroll
    for (int j = 0; j < 4; j++) acc[i][j] = (f32x4){0.f, 0.f, 0.f, 0.f};

  const int c0 = tid, c1 = 256 + tid;
  const int r0 = c0 >> 2, cb0 = (c0 & 3) * 8;
  const int r1 = c1 >> 2, cb1 = (c1 & 3) * 8;
  const _Float16* Ap0 = A + (size_t)(m0 + r0) * DIMC + cb0;
  const _Float16* Ap1 = A + (size_t)(m0 + r1) * DIMC + cb1;
  const _Float16* Wp0 = W + (size_t)(o0 + r0) * DIMC + cb0;
  const _Float16* Wp1 = W + (size_t)(o0 + r1) * DIMC + cb1;

  for (int k0 = 0; k0 < DIMC; k0 += 32) {
    __syncthreads();
    gld16(Ap0 + k0, &Alds[c0 * 8]);
    gld16(Ap1 + k0, &Alds[c1 * 8]);
    gld16(Wp0 + k0, &Blds[c0 * 8]);
    gld16(Wp1 + k0, &Blds[c1 * 8]);
    __syncthreads();

    f16x8 a[4], b[4];
#pragma unroll
    for (int i = 0; i < 4; i++)
      a[i] = *(const f16x8*)&Alds[(wr + i * 16 + l16) * 32 + quad * 8];
#pragma unroll
    for (int j = 0; j < 4; j++)
      b[j] = *(const f16x8*)&Blds[(wc + j * 16 + l16) * 32 + quad * 8];
#pragma unroll
    for (int i = 0; i < 4; i++)
#pragma unroll
      for (int j = 0; j < 4; j++)
        acc[i][j] = __builtin_amdgcn_mfma_f32_16x16x32_f16(a[i], b[j], acc[i][j], 0, 0, 0);
  }

  if constexpr (EPI == 0) {
#pragma unroll
    for (int j = 0; j < 4; j++) {
      const int o = o0 + wc + j * 16 + l16;
      const int part = o / DIMC;
      const int cc = o - part * DIMC;
      const int hh = cc >> 6, d = cc & 63;
      _Float16* dst = (part == 0) ? oq : (part == 1 ? ok : ov);
      const float badd = (part == 0) ? b0[cc] : (part == 2 ? b1[cc] : 0.f);
#pragma unroll
      for (int i = 0; i < 4; i++) {
#pragma unroll
        for (int r = 0; r < 4; r++) {
          const int m = m0 + wr + i * 16 + quad * 4 + r;
          const int bb = m >> 10, n = m & 1023;
          float v = acc[i][j][r];
          if (part == 0) v = (v + badd) * 0.125f;
          else if (part == 2) v += badd;
          dst[(((size_t)(bb * NHH + hh)) * NSEQ + n) * HD + d] = (_Float16)v;
        }
      }
    }
  } else {
#pragma unroll
    for (int j = 0; j < 4; j++) {
      const int o = o0 + wc + j * 16 + l16;
      const float bo = b0[o];
#pragma unroll
      for (int i = 0; i < 4; i++) {
#pragma unroll
        for (int r = 0; r < 4; r++) {
          const int m = m0 + wr + i * 16 + quad * 4 + r;
          outF[(size_t)m * DIMC + o] = acc[i][j][r] + bo;
        }
      }
    }
  }
}

// ---------------------------------------------------------------------------
// V transpose: [bh, n, d] f16 -> [bh, d, n] f16.  64x64 tiles via LDS.
// ---------------------------------------------------------------------------
__global__ __launch_bounds__(256) void vtrans(const _Float16* __restrict__ V,
                                              _Float16* __restrict__ Vt) {
  __shared__ _Float16 T[64 * 72];
  const int bh = blockIdx.y, nt = blockIdx.x, tid = threadIdx.x;
#pragma unroll
  for (int c = 0; c < 2; c++) {
    const int lin = tid * 2 + c;
    const int n = lin >> 3, c8 = (lin & 7) * 8;
    *(f16x8*)&T[n * 72 + c8] =
        *(const f16x8*)(V + ((size_t)(bh * NSEQ + nt * 64 + n)) * HD + c8);
  }
  __syncthreads();
#pragma unroll
  for (int c = 0; c < 2; c++) {
    const int lin = tid * 2 + c;
    const int d = lin >> 3, n8 = (lin & 7) * 8;
    f16x8 o;
#pragma unroll
    for (int j = 0; j < 8; j++) o[j] = T[(n8 + j) * 72 + d];
    *(f16x8*)(Vt + ((size_t)(bh * HD + d)) * NSEQ + nt * 64 + n8) = o;
  }
}

// ---------------------------------------------------------------------------
// Head-major fp32 relative-bias table: relT[h][dy*63+dx] = rel_table[idx][h].
// 190 KB total -> L2-resident, shared by every flash block.
// ---------------------------------------------------------------------------
__global__ __launch_bounds__(256) void relt_pre(const float* __restrict__ rel_table,
                                                float* __restrict__ relT) {
  const int g = blockIdx.x * 256 + threadIdx.x;
  if (g >= NHH * RELN) return;
  const int h = g / RELN, idx = g - h * RELN;
  relT[h * RELP + idx] = rel_table[idx * NHH + h];
}

// ---------------------------------------------------------------------------
// Flash attention, 32x32x16 MFMA transposed compute (S^T = K Q^T, O^T = V^T P^T).
// Block = (head, b, 128 q rows); 4 waves x 32 q-rows (one image row each:
// qy = qt*4+w, qx = ql).  Each 32-key S-tile spans one key image row, so its
// bias is a 63-entry table row: one 252B L1-hot load + ds_bpermute broadcast.
// P^T feeds PV via one shfl_xor(32) half-exchange (no Ps LDS).
// K/V tiles XOR-swizzled in LDS.  No-max softmax, deferred row-sum.
// ---------------------------------------------------------------------------
__global__ __launch_bounds__(256, 3) void flash_mfma(
    const _Float16* __restrict__ Qg, const _Float16* __restrict__ Kg,
    const _Float16* __restrict__ Vtg, const float* __restrict__ relT,
    _Float16* __restrict__ AO) {
  const int yb = blockIdx.y;
  const int head = yb >> 3, b = yb & 7;
  const int bh = b * NHH + head;
  const int qt = blockIdx.x;                  // 0..7 (128 q rows each)
  const int tid = threadIdx.x, w = tid >> 6, lane = tid & 63;
  const int ql = lane & 31;                   // q column within wave tile
  const int hf = lane >> 5;                   // lane half (k/d sub-offset)

  __shared__ _Float16 Klds[128 * 64];         // [row][chunk^key], 8 chunks/row
  __shared__ _Float16 Vlds[64 * 128];         // [d-row][chunk^key], 16 chunks/row

  // persistent Q B-frags: B[n=ql][k = s*16 + hf*8 + j]
  const int qglob = qt * 128 + w * 32 + ql;
  const _Float16* Qrow = Qg + ((size_t)bh * NSEQ + qglob) * HD + hf * 8;
  f16x8 bq[4];
#pragma unroll
  for (int s = 0; s < 4; s++) bq[s] = *(const f16x8*)(Qrow + s * 16);

  f32x16 O0 = {}, O1 = {};                    // O^T d-tiles 0..31, 32..63
  float psum = 0.f;

  const _Float16* Kbase = Kg + (size_t)bh * NSEQ * HD;
  const _Float16* Vtbase = Vtg + (size_t)bh * HD * NSEQ;

  // bias table row machinery: qy fixed per wave; dy = qy - ky + 31
  const float* relTh = relT + (size_t)head * RELP;
  const int qy = qt * 4 + w;
  const int idxb = ql + 31 - 4 * hf;          // bpermute src = idxb - c_r

  // V A-frag row keys (fixed per lane)
  const int vrow0 = ql, vrow1 = 32 + ql;
  const int vkey0 = (vrow0 ^ (vrow0 >> 3)) & 7;
  const int vkey1 = (vrow1 ^ (vrow1 >> 3)) & 7;

  for (int kt = 0; kt < 8; kt++) {
    __syncthreads();
#pragma unroll
    for (int c4 = 0; c4 < 4; c4++) {
      const int c = tid + c4 * 256;
      const int kr = c >> 3, kc = c & 7;
      const int kpos = (kr << 3) | (kc ^ ((kr ^ (kr >> 3)) & 7));
      *(f16x8*)&Klds[kpos * 8] =
          *(const f16x8*)(Kbase + ((size_t)(kt * 128 + kr)) * HD + kc * 8);
      const int vr = c >> 4, vc = c & 15;
      const int vpos = (vr << 4) | (vc ^ ((vr ^ (vr >> 3)) & 7));
      *(f16x8*)&Vlds[vpos * 8] =
          *(const f16x8*)(Vtbase + (size_t)vr * NSEQ + kt * 128 + vc * 8);
    }
    // bias rows for this iteration's 4 key image-rows (L1-hot, 252 B each)
    float rowv[4];
#pragma unroll
    for (int t = 0; t < 4; t++)
      rowv[t] = relTh[(qy - (kt * 4 + t) + 31) * 63 + lane];
    __syncthreads();

#pragma unroll
    for (int t = 0; t < 4; t++) {
      // S^T 32x32 tile: A = K rows (t*32+ql), contraction d (64)
      const int arow = t * 32 + ql;
      const int akey = (arow ^ (arow >> 3)) & 7;
      f32x16 S = {};
#pragma unroll
      for (int s = 0; s < 4; s++) {
        const f16x8 ak = *(const f16x8*)&Klds[((arow << 3) | ((s * 2 + hf) ^ akey)) * 8];
        S = __builtin_amdgcn_mfma_f32_32x32x16_f16(ak, bq[s], S, 0, 0, 0);
      }

      // bias via bpermute from the table row + exp + psum, pack to f16 pairs
      unsigned int dw[8];
#pragma unroll
      for (int i = 0; i < 8; i++) {
        const int r0i = 2 * i, r1i = 2 * i + 1;
        const int c0 = (r0i & 3) + 8 * (r0i >> 2);
        const int c1 = (r1i & 3) + 8 * (r1i >> 2);
        const float bb0 = __shfl(rowv[t], idxb - c0, 64);
        const float bb1 = __shfl(rowv[t], idxb - c1, 64);
        const float p0 = __expf(S[r0i] + bb0);
        const float p1 = __expf(S[r1i] + bb1);
        psum += p0 + p1;
        union { f16x4 h; unsigned int u[2]; } cv;
        cv.h[0] = (_Float16)p0; cv.h[1] = (_Float16)p1;
        dw[i] = cv.u[0];
      }

      // PV: B-frag from P^T via half-exchange; A = V^T rows from LDS
#pragma unroll
      for (int s = 0; s < 2; s++) {
        const unsigned int x0 = hf ? dw[4 * s + 0] : dw[4 * s + 2];
        const unsigned int x1 = hf ? dw[4 * s + 1] : dw[4 * s + 3];
        const unsigned int y0 = (unsigned int)__shfl_xor((int)x0, 32, 64);
        const unsigned int y1 = (unsigned int)__shfl_xor((int)x1, 32, 64);
        union { unsigned int u[4]; f16x8 v; } bp;
        if (hf == 0) {
          bp.u[0] = dw[4 * s + 0]; bp.u[1] = dw[4 * s + 1];
          bp.u[2] = y0;            bp.u[3] = y1;
        } else {
          bp.u[0] = y0;            bp.u[1] = y1;
          bp.u[2] = dw[4 * s + 2]; bp.u[3] = dw[4 * s + 3];
        }
        const int kchunk = t * 4 + s * 2 + hf;
        const f16x8 av0 = *(const f16x8*)&Vlds[((vrow0 << 4) | (kchunk ^ vkey0)) * 8];
        O0 = __builtin_amdgcn_mfma_f32_32x32x16_f16(av0, bp.v, O0, 0, 0, 0);
        const f16x8 av1 = *(const f16x8*)&Vlds[((vrow1 << 4) | (kchunk ^ vkey1)) * 8];
        O1 = __builtin_amdgcn_mfma_f32_32x32x16_f16(av1, bp.v, O1, 0, 0, 0);
      }
    }
  }

  // total row-sum for this lane's q column; divide + store O^T
  psum += __shfl_xor(psum, 32, 64);
  const float inv = 1.f / psum;
  _Float16* aoRow = AO + ((size_t)(b * NSEQ + qglob)) * DIMC + head * HD;
#pragma unroll
  for (int g = 0; g < 4; g++) {
    f16x4 o0, o1;
#pragma unroll
    for (int j = 0; j < 4; j++) {
      o0[j] = (_Float16)(O0[4 * g + j] * inv);
      o1[j] = (_Float16)(O1[4 * g + j] * inv);
    }
    const int d0 = 8 * g + 4 * hf;
    *(f16x4*)(aoRow + d0) = o0;
    *(f16x4*)(aoRow + 32 + d0) = o1;
  }
}

extern "C" void kernel_launch(void* const* d_in, const int* in_sizes, int n_in,
                              void* d_out, int out_size, void* d_ws, size_t ws_size,
                              hipStream_t stream) {
  const float* x        = (const float*)d_in[0];
  const float* qkv_w    = (const float*)d_in[1];
  const float* q_bias   = (const float*)d_in[2];
  const float* v_bias   = (const float*)d_in[3];
  const float* proj_w   = (const float*)d_in[4];
  const float* proj_b   = (const float*)d_in[5];
  const float* rel_tab  = (const float*)d_in[6];
  float* out = (float*)d_out;

  const size_t NTOK = (size_t)8 * NHH * NSEQ * HD;
  _Float16* Xb     = (_Float16*)d_ws;
  _Float16* Wqkvb  = Xb + SX;
  _Float16* Wprojb = Wqkvb + SW1;
  _Float16* Qb     = Wprojb + SW2;
  _Float16* Kb     = Qb + NTOK;
  _Float16* Vb     = Kb + NTOK;
  _Float16* Vt     = Vb + NTOK;
  float*    relT   = (float*)(Vt + NTOK);   // 12*4032 fp32 = 193 KB
  _Float16* AOb    = Xb;                    // alias: x consumed before flash writes

  cast_f16<<<dim3((SX + SW1 + SW2) / 2048), 256, 0, stream>>>(x, qkv_w, proj_w, Xb);

  gemm_mfma<0><<<dim3(2304 / 128, 8192 / 128), 256, 0, stream>>>(
      Xb, Wqkvb, q_bias, v_bias, nullptr, Qb, Kb, Vb);

  vtrans<<<dim3(16, 96), 256, 0, stream>>>(Vb, Vt);

  relt_pre<<<dim3((NHH * RELN + 255) / 256), 256, 0, stream>>>(rel_tab, relT);

  flash_mfma<<<dim3(8, 96), 256, 0, stream>>>(Qb, Kb, Vt, relT, AOb);

  gemm_mfma<1><<<dim3(DIMC / 128, 8192 / 128), 256, 0, stream>>>(
      AOb, Wprojb, proj_b, nullptr, out, nullptr, nullptr, nullptr);
}

// Round 8
// 264.046 us; speedup vs baseline: 1.0501x; 1.0501x over previous
//
#include <hip/hip_runtime.h>
#include <cstdint>
#include <cstddef>

#define DIMC 768
#define NHH  12
#define NSEQ 1024
#define HD   64

#define SX  6291456   // x elems (8*1024*768)
#define SW1 1769472   // qkv_w elems
#define SW2 589824    // proj_w elems

#define RELN 3969     // 63*63 table entries per head
#define RELP 4032     // padded stride (lane-63 overread stays in-bounds)

typedef _Float16 f16x8 __attribute__((ext_vector_type(8)));
typedef _Float16 f16x4 __attribute__((ext_vector_type(4)));
typedef float    f32x4 __attribute__((ext_vector_type(4)));
typedef float    f32x16 __attribute__((ext_vector_type(16)));

__device__ inline void gld16(const _Float16* g, _Float16* l) {
  __builtin_amdgcn_global_load_lds(
      (const __attribute__((address_space(1))) void*)g,
      (__attribute__((address_space(3))) void*)l, 16, 0, 0);
}

// ---------------------------------------------------------------------------
// Fused fp32 -> fp16 cast of x | qkv_w | proj_w into one contiguous ws region.
// ---------------------------------------------------------------------------
__global__ __launch_bounds__(256) void cast_f16(
    const float* __restrict__ x, const float* __restrict__ w1,
    const float* __restrict__ w2, _Float16* __restrict__ dst) {
  const long long t = (long long)blockIdx.x * 256 + threadIdx.x;
  const long long i = t * 8;
  const float* src; long long off;
  if (i < SX) { src = x; off = i; }
  else if (i < SX + SW1) { src = w1; off = i - SX; }
  else { src = w2; off = i - (SX + SW1); }
  const float4 a = *(const float4*)(src + off);
  const float4 b = *(const float4*)(src + off + 4);
  f16x8 o;
  o[0] = (_Float16)a.x; o[1] = (_Float16)a.y; o[2] = (_Float16)a.z; o[3] = (_Float16)a.w;
  o[4] = (_Float16)b.x; o[5] = (_Float16)b.y; o[6] = (_Float16)b.z; o[7] = (_Float16)b.w;
  *(f16x8*)(dst + i) = o;
}

// ---------------------------------------------------------------------------
// MFMA GEMM: C[m,o] = sum_k A[m,k]*W[o,k].  128x128 tile, BK=32, m97 structure.
// EPI==0: scatter f16 Q(+bias,*0.125)/K/V(+bias) into [B,NH,N,hd]
// EPI==1: fp32 outF[m*768+o] = acc + b0[o]
// ---------------------------------------------------------------------------
template <int EPI>
__global__ __launch_bounds__(256) void gemm_mfma(
    const _Float16* __restrict__ A, const _Float16* __restrict__ W,
    const float* __restrict__ b0, const float* __restrict__ b1,
    float* __restrict__ outF, _Float16* __restrict__ oq,
    _Float16* __restrict__ ok, _Float16* __restrict__ ov) {
  __shared__ _Float16 Alds[128 * 32];
  __shared__ _Float16 Blds[128 * 32];

  const int tid = threadIdx.x;
  const int w = tid >> 6, lane = tid & 63, quad = lane >> 4, l16 = lane & 15;
  const int m0 = blockIdx.y * 128, o0 = blockIdx.x * 128;
  const int wr = (w >> 1) * 64, wc = (w & 1) * 64;

  f32x4 acc[4][4];
#pragma unroll
  for (int i = 0; i < 4; i++)
#pragma unroll
    for (int j = 0; j < 4; j++) acc[i][j] = (f32x4){0.f, 0.f, 0.f, 0.f};

  const int c0 = tid, c1 = 256 + tid;
  const int r0 = c0 >> 2, cb0 = (c0 & 3) * 8;
  const int r1 = c1 >> 2, cb1 = (c1 & 3) * 8;
  const _Float16* Ap0 = A + (size_t)(m0 + r0) * DIMC + cb0;
  const _Float16* Ap1 = A + (size_t)(m0 + r1) * DIMC + cb1;
  const _Float16* Wp0 = W + (size_t)(o0 + r0) * DIMC + cb0;
  const _Float16* Wp1 = W + (size_t)(o0 + r1) * DIMC + cb1;

  for (int k0 = 0; k0 < DIMC; k0 += 32) {
    __syncthreads();
    gld16(Ap0 + k0, &Alds[c0 * 8]);
    gld16(Ap1 + k0, &Alds[c1 * 8]);
    gld16(Wp0 + k0, &Blds[c0 * 8]);
    gld16(Wp1 + k0, &Blds[c1 * 8]);
    __syncthreads();

    f16x8 a[4], b[4];
#pragma unroll
    for (int i = 0; i < 4; i++)
      a[i] = *(const f16x8*)&Alds[(wr + i * 16 + l16) * 32 + quad * 8];
#pragma unroll
    for (int j = 0; j < 4; j++)
      b[j] = *(const f16x8*)&Blds[(wc + j * 16 + l16) * 32 + quad * 8];
#pragma unroll
    for (int i = 0; i < 4; i++)
#pragma unroll
      for (int j = 0; j < 4; j++)
        acc[i][j] = __builtin_amdgcn_mfma_f32_16x16x32_f16(a[i], b[j], acc[i][j], 0, 0, 0);
  }

  if constexpr (EPI == 0) {
#pragma unroll
    for (int j = 0; j < 4; j++) {
      const int o = o0 + wc + j * 16 + l16;
      const int part = o / DIMC;
      const int cc = o - part * DIMC;
      const int hh = cc >> 6, d = cc & 63;
      _Float16* dst = (part == 0) ? oq : (part == 1 ? ok : ov);
      const float badd = (part == 0) ? b0[cc] : (part == 2 ? b1[cc] : 0.f);
#pragma unroll
      for (int i = 0; i < 4; i++) {
#pragma unroll
        for (int r = 0; r < 4; r++) {
          const int m = m0 + wr + i * 16 + quad * 4 + r;
          const int bb = m >> 10, n = m & 1023;
          float v = acc[i][j][r];
          if (part == 0) v = (v + badd) * 0.125f;
          else if (part == 2) v += badd;
          dst[(((size_t)(bb * NHH + hh)) * NSEQ + n) * HD + d] = (_Float16)v;
        }
      }
    }
  } else {
#pragma unroll
    for (int j = 0; j < 4; j++) {
      const int o = o0 + wc + j * 16 + l16;
      const float bo = b0[o];
#pragma unroll
      for (int i = 0; i < 4; i++) {
#pragma unroll
        for (int r = 0; r < 4; r++) {
          const int m = m0 + wr + i * 16 + quad * 4 + r;
          outF[(size_t)m * DIMC + o] = acc[i][j][r] + bo;
        }
      }
    }
  }
}

// ---------------------------------------------------------------------------
// V transpose: [bh, n, d] f16 -> [bh, d, n] f16.  64x64 tiles via LDS.
// ---------------------------------------------------------------------------
__global__ __launch_bounds__(256) void vtrans(const _Float16* __restrict__ V,
                                              _Float16* __restrict__ Vt) {
  __shared__ _Float16 T[64 * 72];
  const int bh = blockIdx.y, nt = blockIdx.x, tid = threadIdx.x;
#pragma unroll
  for (int c = 0; c < 2; c++) {
    const int lin = tid * 2 + c;
    const int n = lin >> 3, c8 = (lin & 7) * 8;
    *(f16x8*)&T[n * 72 + c8] =
        *(const f16x8*)(V + ((size_t)(bh * NSEQ + nt * 64 + n)) * HD + c8);
  }
  __syncthreads();
#pragma unroll
  for (int c = 0; c < 2; c++) {
    const int lin = tid * 2 + c;
    const int d = lin >> 3, n8 = (lin & 7) * 8;
    f16x8 o;
#pragma unroll
    for (int j = 0; j < 8; j++) o[j] = T[(n8 + j) * 72 + d];
    *(f16x8*)(Vt + ((size_t)(bh * HD + d)) * NSEQ + nt * 64 + n8) = o;
  }
}

// ---------------------------------------------------------------------------
// Head-major fp32 relative-bias table: relT[h][dy*63+dx] = rel_table[idx][h].
// 190 KB total -> L2-resident, shared by every flash block.
// ---------------------------------------------------------------------------
__global__ __launch_bounds__(256) void relt_pre(const float* __restrict__ rel_table,
                                                float* __restrict__ relT) {
  const int g = blockIdx.x * 256 + threadIdx.x;
  if (g >= NHH * RELN) return;
  const int h = g / RELN, idx = g - h * RELN;
  relT[h * RELP + idx] = rel_table[idx * NHH + h];
}

// ---------------------------------------------------------------------------
// Flash attention, 32x32x16 MFMA transposed compute (S^T = K Q^T, O^T = V^T P^T).
// 1-D grid of 768, decoded bh = n % 96, qt = n / 96: since 96 = 0 (mod 8),
// all 8 qt-blocks sharing one (b,h) K/V slice land on the SAME XCD under
// round-robin dispatch -> slice is HBM-fetched once, L2-served 8x.
// 4 waves x 32 q-rows (one image row each: qy = qt*4+w, qx = ql); bias is a
// 63-entry table row (one 252B L1-hot load + shfl broadcast).  P^T feeds PV
// via one shfl_xor(32) half-exchange (no Ps LDS).  K/V XOR-swizzled in LDS.
// No-max softmax, deferred row-sum.
// ---------------------------------------------------------------------------
__global__ __launch_bounds__(256, 3) void flash_mfma(
    const _Float16* __restrict__ Qg, const _Float16* __restrict__ Kg,
    const _Float16* __restrict__ Vtg, const float* __restrict__ relT,
    _Float16* __restrict__ AO) {
  const int nblk = blockIdx.x;
  const int bhl = nblk % 96;                  // same-XCD group key
  const int qt = nblk / 96;                   // 0..7 (128 q rows each)
  const int head = bhl >> 3, b = bhl & 7;
  const int bh = b * NHH + head;
  const int tid = threadIdx.x, w = tid >> 6, lane = tid & 63;
  const int ql = lane & 31;                   // q column within wave tile
  const int hf = lane >> 5;                   // lane half (k/d sub-offset)

  __shared__ _Float16 Klds[128 * 64];         // [row][chunk^key], 8 chunks/row
  __shared__ _Float16 Vlds[64 * 128];         // [d-row][chunk^key], 16 chunks/row

  // persistent Q B-frags: B[n=ql][k = s*16 + hf*8 + j]
  const int qglob = qt * 128 + w * 32 + ql;
  const _Float16* Qrow = Qg + ((size_t)bh * NSEQ + qglob) * HD + hf * 8;
  f16x8 bq[4];
#pragma unroll
  for (int s = 0; s < 4; s++) bq[s] = *(const f16x8*)(Qrow + s * 16);

  f32x16 O0 = {}, O1 = {};                    // O^T d-tiles 0..31, 32..63
  float psum = 0.f;

  const _Float16* Kbase = Kg + (size_t)bh * NSEQ * HD;
  const _Float16* Vtbase = Vtg + (size_t)bh * HD * NSEQ;

  // bias table row machinery: qy fixed per wave; dy = qy - ky + 31
  const float* relTh = relT + (size_t)head * RELP;
  const int qy = qt * 4 + w;
  const int idxb = ql + 31 - 4 * hf;          // shfl src = idxb - c_r

  // V A-frag row keys (fixed per lane)
  const int vrow0 = ql, vrow1 = 32 + ql;
  const int vkey0 = (vrow0 ^ (vrow0 >> 3)) & 7;
  const int vkey1 = (vrow1 ^ (vrow1 >> 3)) & 7;

  for (int kt = 0; kt < 8; kt++) {
    __syncthreads();
#pragma unroll
    for (int c4 = 0; c4 < 4; c4++) {
      const int c = tid + c4 * 256;
      const int kr = c >> 3, kc = c & 7;
      const int kpos = (kr << 3) | (kc ^ ((kr ^ (kr >> 3)) & 7));
      *(f16x8*)&Klds[kpos * 8] =
          *(const f16x8*)(Kbase + ((size_t)(kt * 128 + kr)) * HD + kc * 8);
      const int vr = c >> 4, vc = c & 15;
      const int vpos = (vr << 4) | (vc ^ ((vr ^ (vr >> 3)) & 7));
      *(f16x8*)&Vlds[vpos * 8] =
          *(const f16x8*)(Vtbase + (size_t)vr * NSEQ + kt * 128 + vc * 8);
    }
    // bias rows for this iteration's 4 key image-rows (L1-hot, 252 B each)
    float rowv[4];
#pragma unroll
    for (int t = 0; t < 4; t++)
      rowv[t] = relTh[(qy - (kt * 4 + t) + 31) * 63 + lane];
    __syncthreads();

#pragma unroll
    for (int t = 0; t < 4; t++) {
      // S^T 32x32 tile: A = K rows (t*32+ql), contraction d (64)
      const int arow = t * 32 + ql;
      const int akey = (arow ^ (arow >> 3)) & 7;
      f32x16 S = {};
#pragma unroll
      for (int s = 0; s < 4; s++) {
        const f16x8 ak = *(const f16x8*)&Klds[((arow << 3) | ((s * 2 + hf) ^ akey)) * 8];
        S = __builtin_amdgcn_mfma_f32_32x32x16_f16(ak, bq[s], S, 0, 0, 0);
      }

      // bias via shfl from the table row + exp + psum, pack to f16 pairs
      unsigned int dw[8];
#pragma unroll
      for (int i = 0; i < 8; i++) {
        const int r0i = 2 * i, r1i = 2 * i + 1;
        const int c0 = (r0i & 3) + 8 * (r0i >> 2);
        const int c1 = (r1i & 3) + 8 * (r1i >> 2);
        const float bb0 = __shfl(rowv[t], idxb - c0, 64);
        const float bb1 = __shfl(rowv[t], idxb - c1, 64);
        const float p0 = __expf(S[r0i] + bb0);
        const float p1 = __expf(S[r1i] + bb1);
        psum += p0 + p1;
        union { f16x4 h; unsigned int u[2]; } cv;
        cv.h[0] = (_Float16)p0; cv.h[1] = (_Float16)p1;
        dw[i] = cv.u[0];
      }

      // PV: B-frag from P^T via half-exchange; A = V^T rows from LDS
#pragma unroll
      for (int s = 0; s < 2; s++) {
        const unsigned int x0 = hf ? dw[4 * s + 0] : dw[4 * s + 2];
        const unsigned int x1 = hf ? dw[4 * s + 1] : dw[4 * s + 3];
        const unsigned int y0 = (unsigned int)__shfl_xor((int)x0, 32, 64);
        const unsigned int y1 = (unsigned int)__shfl_xor((int)x1, 32, 64);
        union { unsigned int u[4]; f16x8 v; } bp;
        if (hf == 0) {
          bp.u[0] = dw[4 * s + 0]; bp.u[1] = dw[4 * s + 1];
          bp.u[2] = y0;            bp.u[3] = y1;
        } else {
          bp.u[0] = y0;            bp.u[1] = y1;
          bp.u[2] = dw[4 * s + 2]; bp.u[3] = dw[4 * s + 3];
        }
        const int kchunk = t * 4 + s * 2 + hf;
        const f16x8 av0 = *(const f16x8*)&Vlds[((vrow0 << 4) | (kchunk ^ vkey0)) * 8];
        O0 = __builtin_amdgcn_mfma_f32_32x32x16_f16(av0, bp.v, O0, 0, 0, 0);
        const f16x8 av1 = *(const f16x8*)&Vlds[((vrow1 << 4) | (kchunk ^ vkey1)) * 8];
        O1 = __builtin_amdgcn_mfma_f32_32x32x16_f16(av1, bp.v, O1, 0, 0, 0);
      }
    }
  }

  // total row-sum for this lane's q column; divide + store O^T
  psum += __shfl_xor(psum, 32, 64);
  const float inv = 1.f / psum;
  _Float16* aoRow = AO + ((size_t)(b * NSEQ + qglob)) * DIMC + head * HD;
#pragma unroll
  for (int g = 0; g < 4; g++) {
    f16x4 o0, o1;
#pragma unroll
    for (int j = 0; j < 4; j++) {
      o0[j] = (_Float16)(O0[4 * g + j] * inv);
      o1[j] = (_Float16)(O1[4 * g + j] * inv);
    }
    const int d0 = 8 * g + 4 * hf;
    *(f16x4*)(aoRow + d0) = o0;
    *(f16x4*)(aoRow + 32 + d0) = o1;
  }
}

extern "C" void kernel_launch(void* const* d_in, const int* in_sizes, int n_in,
                              void* d_out, int out_size, void* d_ws, size_t ws_size,
                              hipStream_t stream) {
  const float* x        = (const float*)d_in[0];
  const float* qkv_w    = (const float*)d_in[1];
  const float* q_bias   = (const float*)d_in[2];
  const float* v_bias   = (const float*)d_in[3];
  const float* proj_w   = (const float*)d_in[4];
  const float* proj_b   = (const float*)d_in[5];
  const float* rel_tab  = (const float*)d_in[6];
  float* out = (float*)d_out;

  const size_t NTOK = (size_t)8 * NHH * NSEQ * HD;
  _Float16* Xb     = (_Float16*)d_ws;
  _Float16* Wqkvb  = Xb + SX;
  _Float16* Wprojb = Wqkvb + SW1;
  _Float16* Qb     = Wprojb + SW2;
  _Float16* Kb     = Qb + NTOK;
  _Float16* Vb     = Kb + NTOK;
  _Float16* Vt     = Vb + NTOK;
  float*    relT   = (float*)(Vt + NTOK);   // 12*4032 fp32 = 193 KB
  _Float16* AOb    = Xb;                    // alias: x consumed before flash writes

  cast_f16<<<dim3((SX + SW1 + SW2) / 2048), 256, 0, stream>>>(x, qkv_w, proj_w, Xb);

  gemm_mfma<0><<<dim3(2304 / 128, 8192 / 128), 256, 0, stream>>>(
      Xb, Wqkvb, q_bias, v_bias, nullptr, Qb, Kb, Vb);

  vtrans<<<dim3(16, 96), 256, 0, stream>>>(Vb, Vt);

  relt_pre<<<dim3((NHH * RELN + 255) / 256), 256, 0, stream>>>(rel_tab, relT);

  flash_mfma<<<dim3(768), 256, 0, stream>>>(Qb, Kb, Vt, relT, AOb);

  gemm_mfma<1><<<dim3(DIMC / 128, 8192 / 128), 256, 0, stream>>>(
      AOb, Wprojb, proj_b, nullptr, out, nullptr, nullptr, nullptr);
}

// Round 9
// 236.690 us; speedup vs baseline: 1.1715x; 1.1156x over previous
//
#include <hip/hip_runtime.h>
#include <cstdint>
#include <cstddef>

#define DIMC 768
#define NHH  12
#define NSEQ 1024
#define HD   64

#define SX  6291456   // x elems (8*1024*768)
#define SW1 1769472   // qkv_w elems
#define SW2 589824    // proj_w elems

#define RELN 3969     // 63*63 table entries per head
#define RELP 4032     // padded stride

typedef _Float16 f16x8 __attribute__((ext_vector_type(8)));
typedef _Float16 f16x4 __attribute__((ext_vector_type(4)));
typedef float    f32x4 __attribute__((ext_vector_type(4)));
typedef float    f32x16 __attribute__((ext_vector_type(16)));
typedef float    f32x4u __attribute__((ext_vector_type(4), aligned(4)));  // 4B-aligned gather

__device__ inline void gld16(const _Float16* g, _Float16* l) {
  __builtin_amdgcn_global_load_lds(
      (const __attribute__((address_space(1))) void*)g,
      (__attribute__((address_space(3))) void*)l, 16, 0, 0);
}

// ---------------------------------------------------------------------------
// Fused fp32 -> fp16 cast of x | qkv_w | proj_w into one contiguous ws region.
// ---------------------------------------------------------------------------
__global__ __launch_bounds__(256) void cast_f16(
    const float* __restrict__ x, const float* __restrict__ w1,
    const float* __restrict__ w2, _Float16* __restrict__ dst) {
  const long long t = (long long)blockIdx.x * 256 + threadIdx.x;
  const long long i = t * 8;
  const float* src; long long off;
  if (i < SX) { src = x; off = i; }
  else if (i < SX + SW1) { src = w1; off = i - SX; }
  else { src = w2; off = i - (SX + SW1); }
  const float4 a = *(const float4*)(src + off);
  const float4 b = *(const float4*)(src + off + 4);
  f16x8 o;
  o[0] = (_Float16)a.x; o[1] = (_Float16)a.y; o[2] = (_Float16)a.z; o[3] = (_Float16)a.w;
  o[4] = (_Float16)b.x; o[5] = (_Float16)b.y; o[6] = (_Float16)b.z; o[7] = (_Float16)b.w;
  *(f16x8*)(dst + i) = o;
}

// ---------------------------------------------------------------------------
// MFMA GEMM: C[m,o] = sum_k A[m,k]*W[o,k].  128x128 tile, BK=32, m97 structure.
// 1-D grid, XCD-swizzled: m_idx = n & 63 (64 = 0 mod 8 -> same-A-panel blocks
// share an XCD; A is HBM-fetched once, L2-served).
// EPI==0: scatter f16 Q(+bias,*0.125)->[B,NH,N,hd], K->[B,NH,N,hd],
//         V(+bias)->Vt[B,NH,hd,N] (transposed write; vtrans kernel fused away)
// EPI==1: fp32 outF[m*768+o] = acc + b0[o]
// ---------------------------------------------------------------------------
template <int EPI>
__global__ __launch_bounds__(256) void gemm_mfma(
    const _Float16* __restrict__ A, const _Float16* __restrict__ W,
    const float* __restrict__ b0, const float* __restrict__ b1,
    float* __restrict__ outF, _Float16* __restrict__ oq,
    _Float16* __restrict__ ok, _Float16* __restrict__ ovt) {
  __shared__ _Float16 Alds[128 * 32];
  __shared__ _Float16 Blds[128 * 32];

  const int tid = threadIdx.x;
  const int w = tid >> 6, lane = tid & 63, quad = lane >> 4, l16 = lane & 15;
  const int m0 = (blockIdx.x & 63) << 7;
  const int o0 = (blockIdx.x >> 6) << 7;
  const int wr = (w >> 1) * 64, wc = (w & 1) * 64;

  f32x4 acc[4][4];
#pragma unroll
  for (int i = 0; i < 4; i++)
#pragma unroll
    for (int j = 0; j < 4; j++) acc[i][j] = (f32x4){0.f, 0.f, 0.f, 0.f};

  const int c0 = tid, c1 = 256 + tid;
  const int r0 = c0 >> 2, cb0 = (c0 & 3) * 8;
  const int r1 = c1 >> 2, cb1 = (c1 & 3) * 8;
  const _Float16* Ap0 = A + (size_t)(m0 + r0) * DIMC + cb0;
  const _Float16* Ap1 = A + (size_t)(m0 + r1) * DIMC + cb1;
  const _Float16* Wp0 = W + (size_t)(o0 + r0) * DIMC + cb0;
  const _Float16* Wp1 = W + (size_t)(o0 + r1) * DIMC + cb1;

  for (int k0 = 0; k0 < DIMC; k0 += 32) {
    __syncthreads();
    gld16(Ap0 + k0, &Alds[c0 * 8]);
    gld16(Ap1 + k0, &Alds[c1 * 8]);
    gld16(Wp0 + k0, &Blds[c0 * 8]);
    gld16(Wp1 + k0, &Blds[c1 * 8]);
    __syncthreads();

    f16x8 a[4], b[4];
#pragma unroll
    for (int i = 0; i < 4; i++)
      a[i] = *(const f16x8*)&Alds[(wr + i * 16 + l16) * 32 + quad * 8];
#pragma unroll
    for (int j = 0; j < 4; j++)
      b[j] = *(const f16x8*)&Blds[(wc + j * 16 + l16) * 32 + quad * 8];
#pragma unroll
    for (int i = 0; i < 4; i++)
#pragma unroll
      for (int j = 0; j < 4; j++)
        acc[i][j] = __builtin_amdgcn_mfma_f32_16x16x32_f16(a[i], b[j], acc[i][j], 0, 0, 0);
  }

  if constexpr (EPI == 0) {
#pragma unroll
    for (int j = 0; j < 4; j++) {
      const int o = o0 + wc + j * 16 + l16;
      const int part = o / DIMC;
      const int cc = o - part * DIMC;
      const int hh = cc >> 6, d = cc & 63;
      const float badd = (part == 0) ? b0[cc] : (part == 2 ? b1[cc] : 0.f);
      if (part == 2) {
        // V: write transposed into Vt[bh][d][n], f16x4 along n
#pragma unroll
        for (int i = 0; i < 4; i++) {
          const int mb = m0 + wr + i * 16 + quad * 4;
          const int bb = mb >> 10, n0 = mb & 1023;
          f16x4 vv;
#pragma unroll
          for (int r = 0; r < 4; r++) vv[r] = (_Float16)(acc[i][j][r] + badd);
          *(f16x4*)(ovt + (((size_t)(bb * NHH + hh)) * HD + d) * NSEQ + n0) = vv;
        }
      } else {
        _Float16* dst = (part == 0) ? oq : ok;
#pragma unroll
        for (int i = 0; i < 4; i++) {
#pragma unroll
          for (int r = 0; r < 4; r++) {
            const int m = m0 + wr + i * 16 + quad * 4 + r;
            const int bb = m >> 10, n = m & 1023;
            float v = acc[i][j][r];
            if (part == 0) v = (v + badd) * 0.125f;
            dst[(((size_t)(bb * NHH + hh)) * NSEQ + n) * HD + d] = (_Float16)v;
          }
        }
      }
    }
  } else {
#pragma unroll
    for (int j = 0; j < 4; j++) {
      const int o = o0 + wc + j * 16 + l16;
      const float bo = b0[o];
#pragma unroll
      for (int i = 0; i < 4; i++) {
#pragma unroll
        for (int r = 0; r < 4; r++) {
          const int m = m0 + wr + i * 16 + quad * 4 + r;
          outF[(size_t)m * DIMC + o] = acc[i][j][r] + bo;
        }
      }
    }
  }
}

// ---------------------------------------------------------------------------
// Head-major fp32 relative-bias table: relT[h][dy*63+dx] = rel_table[idx][h].
// 190 KB total -> L2-resident, shared by every flash block.
// ---------------------------------------------------------------------------
__global__ __launch_bounds__(256) void relt_pre(const float* __restrict__ rel_table,
                                                float* __restrict__ relT) {
  const int g = blockIdx.x * 256 + threadIdx.x;
  if (g >= NHH * RELN) return;
  const int h = g / RELN, idx = g - h * RELN;
  relT[h * RELP + idx] = rel_table[idx * NHH + h];
}

// ---------------------------------------------------------------------------
// Flash attention, 32x32x16 MFMA transposed compute (S^T = K Q^T, O^T = V^T P^T).
// 1-D grid of 768, bh = n % 96 (96 = 0 mod 8 -> all 8 qt-blocks of one (b,h)
// share an XCD; K/V slice HBM-fetched once, L2-served 8x).
// Bias: reg r=4g+j of an S^T tile needs relT row entry [idxb-8g-j] -- four
// consecutive entries reversed -> one 4B-aligned float4 L1 gather per (t,g)
// (replaces 64 bpermutes/kt from round 8).  P^T feeds PV via one shfl_xor(32)
// half-exchange.  K/V XOR-swizzled in LDS.  No-max softmax, deferred row-sum.
// ---------------------------------------------------------------------------
__global__ __launch_bounds__(256, 3) void flash_mfma(
    const _Float16* __restrict__ Qg, const _Float16* __restrict__ Kg,
    const _Float16* __restrict__ Vtg, const float* __restrict__ relT,
    _Float16* __restrict__ AO) {
  const int nblk = blockIdx.x;
  const int bhl = nblk % 96;                  // same-XCD group key
  const int qt = nblk / 96;                   // 0..7 (128 q rows each)
  const int head = bhl >> 3, b = bhl & 7;
  const int bh = b * NHH + head;
  const int tid = threadIdx.x, w = tid >> 6, lane = tid & 63;
  const int ql = lane & 31;                   // q column within wave tile
  const int hf = lane >> 5;                   // lane half (k/d sub-offset)

  __shared__ _Float16 Klds[128 * 64];         // [row][chunk^key], 8 chunks/row
  __shared__ _Float16 Vlds[64 * 128];         // [d-row][chunk^key], 16 chunks/row

  // persistent Q B-frags: B[n=ql][k = s*16 + hf*8 + j]
  const int qglob = qt * 128 + w * 32 + ql;
  const _Float16* Qrow = Qg + ((size_t)bh * NSEQ + qglob) * HD + hf * 8;
  f16x8 bq[4];
#pragma unroll
  for (int s = 0; s < 4; s++) bq[s] = *(const f16x8*)(Qrow + s * 16);

  f32x16 O0 = {}, O1 = {};                    // O^T d-tiles 0..31, 32..63
  float psum = 0.f;

  const _Float16* Kbase = Kg + (size_t)bh * NSEQ * HD;
  const _Float16* Vtbase = Vtg + (size_t)bh * HD * NSEQ;

  // bias gather machinery: qy fixed per wave; dy = qy - ky + 31
  const float* relTh = relT + (size_t)head * RELP;
  const int qy = qt * 4 + w;
  const int idxb = ql + 31 - 4 * hf;          // dx = idxb - (r&3) - 8*(r>>2)

  // V A-frag row keys (fixed per lane)
  const int vrow0 = ql, vrow1 = 32 + ql;
  const int vkey0 = (vrow0 ^ (vrow0 >> 3)) & 7;
  const int vkey1 = (vrow1 ^ (vrow1 >> 3)) & 7;

  for (int kt = 0; kt < 8; kt++) {
    __syncthreads();
#pragma unroll
    for (int c4 = 0; c4 < 4; c4++) {
      const int c = tid + c4 * 256;
      const int kr = c >> 3, kc = c & 7;
      const int kpos = (kr << 3) | (kc ^ ((kr ^ (kr >> 3)) & 7));
      *(f16x8*)&Klds[kpos * 8] =
          *(const f16x8*)(Kbase + ((size_t)(kt * 128 + kr)) * HD + kc * 8);
      const int vr = c >> 4, vc = c & 15;
      const int vpos = (vr << 4) | (vc ^ ((vr ^ (vr >> 3)) & 7));
      *(f16x8*)&Vlds[vpos * 8] =
          *(const f16x8*)(Vtbase + (size_t)vr * NSEQ + kt * 128 + vc * 8);
    }
    __syncthreads();

#pragma unroll
    for (int t = 0; t < 4; t++) {
      // S^T 32x32 tile: A = K rows (t*32+ql), contraction d (64)
      const int arow = t * 32 + ql;
      const int akey = (arow ^ (arow >> 3)) & 7;
      f32x16 S = {};
#pragma unroll
      for (int s = 0; s < 4; s++) {
        const f16x8 ak = *(const f16x8*)&Klds[((arow << 3) | ((s * 2 + hf) ^ akey)) * 8];
        S = __builtin_amdgcn_mfma_f32_32x32x16_f16(ak, bq[s], S, 0, 0, 0);
      }

      // bias via float4 gathers (row is L1-hot) + exp + psum, pack f16 pairs
      const float* rowb = relTh + (qy - (kt * 4 + t) + 31) * 63 + idxb;
      unsigned int dw[8];
#pragma unroll
      for (int g = 0; g < 4; g++) {
        const f32x4u bv = *(const f32x4u*)(rowb - 8 * g - 3);  // [j=3,2,1,0]
        const float p0 = __expf(S[4 * g + 0] + bv[3]);
        const float p1 = __expf(S[4 * g + 1] + bv[2]);
        const float p2 = __expf(S[4 * g + 2] + bv[1]);
        const float p3 = __expf(S[4 * g + 3] + bv[0]);
        psum += (p0 + p1) + (p2 + p3);
        union { f16x4 h; unsigned int u[2]; } cv;
        cv.h[0] = (_Float16)p0; cv.h[1] = (_Float16)p1;
        cv.h[2] = (_Float16)p2; cv.h[3] = (_Float16)p3;
        dw[2 * g] = cv.u[0]; dw[2 * g + 1] = cv.u[1];
      }

      // PV: B-frag from P^T via half-exchange; A = V^T rows from LDS
#pragma unroll
      for (int s = 0; s < 2; s++) {
        const unsigned int x0 = hf ? dw[4 * s + 0] : dw[4 * s + 2];
        const unsigned int x1 = hf ? dw[4 * s + 1] : dw[4 * s + 3];
        const unsigned int y0 = (unsigned int)__shfl_xor((int)x0, 32, 64);
        const unsigned int y1 = (unsigned int)__shfl_xor((int)x1, 32, 64);
        union { unsigned int u[4]; f16x8 v; } bp;
        if (hf == 0) {
          bp.u[0] = dw[4 * s + 0]; bp.u[1] = dw[4 * s + 1];
          bp.u[2] = y0;            bp.u[3] = y1;
        } else {
          bp.u[0] = y0;            bp.u[1] = y1;
          bp.u[2] = dw[4 * s + 2]; bp.u[3] = dw[4 * s + 3];
        }
        const int kchunk = t * 4 + s * 2 + hf;
        const f16x8 av0 = *(const f16x8*)&Vlds[((vrow0 << 4) | (kchunk ^ vkey0)) * 8];
        O0 = __builtin_amdgcn_mfma_f32_32x32x16_f16(av0, bp.v, O0, 0, 0, 0);
        const f16x8 av1 = *(const f16x8*)&Vlds[((vrow1 << 4) | (kchunk ^ vkey1)) * 8];
        O1 = __builtin_amdgcn_mfma_f32_32x32x16_f16(av1, bp.v, O1, 0, 0, 0);
      }
    }
  }

  // total row-sum for this lane's q column; divide + store O^T
  psum += __shfl_xor(psum, 32, 64);
  const float inv = 1.f / psum;
  _Float16* aoRow = AO + ((size_t)(b * NSEQ + qglob)) * DIMC + head * HD;
#pragma unroll
  for (int g = 0; g < 4; g++) {
    f16x4 o0, o1;
#pragma unroll
    for (int j = 0; j < 4; j++) {
      o0[j] = (_Float16)(O0[4 * g + j] * inv);
      o1[j] = (_Float16)(O1[4 * g + j] * inv);
    }
    const int d0 = 8 * g + 4 * hf;
    *(f16x4*)(aoRow + d0) = o0;
    *(f16x4*)(aoRow + 32 + d0) = o1;
  }
}

extern "C" void kernel_launch(void* const* d_in, const int* in_sizes, int n_in,
                              void* d_out, int out_size, void* d_ws, size_t ws_size,
                              hipStream_t stream) {
  const float* x        = (const float*)d_in[0];
  const float* qkv_w    = (const float*)d_in[1];
  const float* q_bias   = (const float*)d_in[2];
  const float* v_bias   = (const float*)d_in[3];
  const float* proj_w   = (const float*)d_in[4];
  const float* proj_b   = (const float*)d_in[5];
  const float* rel_tab  = (const float*)d_in[6];
  float* out = (float*)d_out;

  const size_t NTOK = (size_t)8 * NHH * NSEQ * HD;
  _Float16* Xb     = (_Float16*)d_ws;
  _Float16* Wqkvb  = Xb + SX;
  _Float16* Wprojb = Wqkvb + SW1;
  _Float16* Qb     = Wprojb + SW2;
  _Float16* Kb     = Qb + NTOK;
  _Float16* Vt     = Kb + NTOK;             // V written transposed by qkv gemm
  float*    relT   = (float*)(Vt + NTOK);   // 12*4032 fp32 = 193 KB
  _Float16* AOb    = Xb;                    // alias: x consumed before flash writes

  cast_f16<<<dim3((SX + SW1 + SW2) / 2048), 256, 0, stream>>>(x, qkv_w, proj_w, Xb);

  relt_pre<<<dim3((NHH * RELN + 255) / 256), 256, 0, stream>>>(rel_tab, relT);

  gemm_mfma<0><<<dim3(64 * 18), 256, 0, stream>>>(
      Xb, Wqkvb, q_bias, v_bias, nullptr, Qb, Kb, Vt);

  flash_mfma<<<dim3(768), 256, 0, stream>>>(Qb, Kb, Vt, relT, AOb);

  gemm_mfma<1><<<dim3(64 * 6), 256, 0, stream>>>(
      AOb, Wprojb, proj_b, nullptr, out, nullptr, nullptr, nullptr);
}